// Round 3
// baseline (190.607 us; speedup 1.0000x reference)
//
#include <hip/hip_runtime.h>
#include <math.h>

#define B_SZ 32768
#define C_SZ 1000
#define NV4  250          // C_SZ/4 vec4 per row (4000 B per row, 16B-aligned)

typedef float fvec4 __attribute__((ext_vector_type(4)));

__constant__ float kMAGIC = 0.165745444183859f;

// ---------------- Kernel 1: fused prep + per-row loss partials ----------------
// (Resubmit of R2 kernel — previous bench failed on container infra, not code.)
//
// Block-local replication of the C=1000 prep reductions (8 KB, L2-hot; same
// 256-thread strided+tree structure as the original prep_kernel -> scalars
// bit-identical). Then one wave per row, TWO rows in flight per wave so 8 KB
// of nontemporal loads are outstanding while the previous rows' exp/reduce
// tail executes (memory duty-cycle fix; T14-style issue-early).
//
// Margin as post-correction: s_adj = s - exp(x_t) + exp(x_t - bm); x_t is
// extracted from the already-loaded registers via wave-uniform indices and
// ONE owner-lane shuffle (replaces a 6-deep shfl_xor chain).
__global__ __launch_bounds__(256) void main_kernel(const float* __restrict__ x,
                                                   const int*   __restrict__ targets,
                                                   const float* __restrict__ cls,
                                                   const float* __restrict__ diff,
                                                   const int*   __restrict__ epoch_p,
                                                   float*       __restrict__ partials) {
    __shared__ float smin[256], ssum[256], smax[256];
    const int tid = threadIdx.x;

    // ---- block-local prep reductions (identical to original prep_kernel) ----
    float mn = INFINITY, sm = 0.f, mx = -INFINITY;
    for (int c = tid; c < C_SZ; c += 256) {
        float v = cls[c];
        mn = fminf(mn, v);
        sm += v;
        mx = fmaxf(mx, diff[c]);
    }
    smin[tid] = mn; ssum[tid] = sm; smax[tid] = mx;
    __syncthreads();
    for (int s = 128; s > 0; s >>= 1) {
        if (tid < s) {
            smin[tid] = fminf(smin[tid], smin[tid + s]);
            ssum[tid] += ssum[tid + s];
            smax[tid] = fmaxf(smax[tid], smax[tid + s]);
        }
        __syncthreads();
    }
    __shared__ float sh_maxm, sh_minc, sh_wsc, sh_ee2;
    if (tid == 0) {
        const float minc = smin[0], sumc = ssum[0], maxd = smax[0];
        const float maxm = -logf(minc / sumc) - kMAGIC;
        const float maxw = 0.5f * maxd * maxd + 0.3f;   // ALPHA*d^P + BETA, P=2
        const int epoch = epoch_p[0];
        float ee2;
        if (epoch < 60)       ee2 = 0.f;
        else if (epoch >= 80) ee2 = 0.5f;               // ee=1, /2
        else                  ee2 = 0.5f * (float)(epoch - 60) / 20.0f;
        sh_maxm = maxm; sh_minc = minc; sh_wsc = maxm / maxw; sh_ee2 = ee2;
    }
    __syncthreads();
    const float maxm = sh_maxm, minc = sh_minc, wsc = sh_wsc, ee2 = sh_ee2;

    // ---- per-row loss: wave gw handles rows gw, gw+8192, gw+16384, gw+24576,
    //      two at a time (same accumulation order as the 1-row version) ----
    const int lane = tid & 63;
    const int wv   = tid >> 6;
    const int gw   = blockIdx.x * 4 + wv;              // 0..8191 (grid = 2048)

    float acc = 0.f;
    #pragma unroll
    for (int half = 0; half < 2; ++half) {
        const int r0 = gw + half * 16384;
        const int r1 = r0 + 8192;

        const int t0 = targets[r0];                    // wave-uniform
        const int t1 = targets[r1];
        // margin operands: issue early, L1/L2-hot (8 KB tables)
        const float c0 = cls[t0],  d0 = diff[t0];
        const float c1 = cls[t1],  d1 = diff[t1];

        const fvec4* __restrict__ xr0 = (const fvec4*)(x + (size_t)r0 * C_SZ);
        const fvec4* __restrict__ xr1 = (const fvec4*)(x + (size_t)r1 * C_SZ);

        // 8 KB of streaming loads in flight before any compute
        fvec4 a[4], b[4];
        #pragma unroll
        for (int k = 0; k < 4; ++k) {
            const int i4 = lane + 64 * k;
            if (i4 < NV4) a[k] = __builtin_nontemporal_load(&xr0[i4]);
            else          a[k] = (fvec4){0.f, 0.f, 0.f, 0.f};
        }
        #pragma unroll
        for (int k = 0; k < 4; ++k) {
            const int i4 = lane + 64 * k;
            if (i4 < NV4) b[k] = __builtin_nontemporal_load(&xr1[i4]);
            else          b[k] = (fvec4){0.f, 0.f, 0.f, 0.f};
        }

        const float bm0 = maxm * sqrtf(minc / c0) + (0.5f * d0 * d0 + 0.3f) * wsc * ee2;
        const float bm1 = maxm * sqrtf(minc / c1) + (0.5f * d1 * d1 + 0.3f) * wsc * ee2;

        // per-row exp-sums (same per-row order as before -> bitwise identical)
        float s0 = 0.f, s1 = 0.f;
        #pragma unroll
        for (int k = 0; k < 4; ++k) {
            const int i4 = lane + 64 * k;
            if (i4 < NV4) {
                s0 += __expf(a[k].x); s0 += __expf(a[k].y);
                s0 += __expf(a[k].z); s0 += __expf(a[k].w);
            }
        }
        #pragma unroll
        for (int k = 0; k < 4; ++k) {
            const int i4 = lane + 64 * k;
            if (i4 < NV4) {
                s1 += __expf(b[k].x); s1 += __expf(b[k].y);
                s1 += __expf(b[k].z); s1 += __expf(b[k].w);
            }
        }
        // two independent shfl chains, interleaved so their latencies overlap
        #pragma unroll
        for (int off = 32; off > 0; off >>= 1) {
            s0 += __shfl_xor(s0, off);
            s1 += __shfl_xor(s1, off);
        }

        // owner-lane extraction of x_t: all indices wave-uniform, ONE shuffle.
        // p0/p1 are computed unconditionally from registers valid on every lane
        // (a[]/b[] are zero-filled past NV4), so the shfl source is defined.
        const int t40 = t0 >> 2, tm0 = t0 & 3, kq0 = t40 >> 6, tl0 = t40 & 63;
        const int t41 = t1 >> 2, tm1 = t1 & 3, kq1 = t41 >> 6, tl1 = t41 & 63;
        fvec4 vo0 = (kq0 == 0) ? a[0] : (kq0 == 1) ? a[1] : (kq0 == 2) ? a[2] : a[3];
        fvec4 vo1 = (kq1 == 0) ? b[0] : (kq1 == 1) ? b[1] : (kq1 == 2) ? b[2] : b[3];
        const float p0 = (tm0 & 2) ? ((tm0 & 1) ? vo0.w : vo0.z)
                                   : ((tm0 & 1) ? vo0.y : vo0.x);
        const float p1 = (tm1 & 2) ? ((tm1 & 1) ? vo1.w : vo1.z)
                                   : ((tm1 & 1) ? vo1.y : vo1.x);
        const float xt0 = __shfl(p0, tl0);
        const float xt1 = __shfl(p1, tl1);

        // replace exp(x_t) by exp(x_t - bm); s >> exp(x_t), no cancellation risk
        const float xadj0 = xt0 - bm0;
        const float xadj1 = xt1 - bm1;
        const float sa0 = s0 - __expf(xt0) + __expf(xadj0);
        const float sa1 = s1 - __expf(xt1) + __expf(xadj1);
        acc += __logf(sa0) - xadj0;      // row order: gw, gw+8192, (then +16384, +24576)
        acc += __logf(sa1) - xadj1;
    }

    __shared__ float sw[4];
    if (lane == 0) sw[wv] = acc;
    __syncthreads();
    if (tid == 0)
        partials[blockIdx.x] = sw[0] + sw[1] + sw[2] + sw[3];
}

// ---------------- Kernel 2: final reduce -> loss ----------------
__global__ void finish_kernel(const float* __restrict__ partials, int n,
                              float* __restrict__ out) {
    __shared__ float sh[256];
    const int tid = threadIdx.x;
    float s = 0.f;
    for (int i = tid; i < n; i += 256) s += partials[i];
    sh[tid] = s;
    __syncthreads();
    for (int k = 128; k > 0; k >>= 1) {
        if (tid < k) sh[tid] += sh[tid + k];
        __syncthreads();
    }
    if (tid == 0) out[0] = sh[0] / (float)B_SZ;
}

extern "C" void kernel_launch(void* const* d_in, const int* in_sizes, int n_in,
                              void* d_out, int out_size, void* d_ws, size_t ws_size,
                              hipStream_t stream) {
    const float* x       = (const float*)d_in[0];
    const int*   targets = (const int*)d_in[1];
    const float* cls     = (const float*)d_in[2];
    const float* diff    = (const float*)d_in[3];
    const int*   epoch   = (const int*)d_in[4];
    float*       out     = (float*)d_out;

    float* partials = (float*)d_ws;          // grid floats

    const int grid = 2048;                   // 8192 waves, 2x2 rows each
    main_kernel<<<grid, 256, 0, stream>>>(x, targets, cls, diff, epoch, partials);

    finish_kernel<<<1, 256, 0, stream>>>(partials, grid, out);
}

// Round 4
// 185.550 us; speedup vs baseline: 1.0273x; 1.0273x over previous
//
#include <hip/hip_runtime.h>
#include <math.h>

#define B_SZ 32768
#define C_SZ 1000
#define NV4  250          // C_SZ/4 vec4 per row (4000 B per row, 16B-aligned)

typedef float fvec4 __attribute__((ext_vector_type(4)));

__constant__ float kMAGIC = 0.165745444183859f;

// ---------------- Kernel 1: fused prep + per-row loss partials ----------------
// R1 structure (best measured: 187.4 us). One row in flight per wave — the
// 2-row variant cost +32 VGPR and dropped occupancy 8->6 waves/SIMD (regressed
// to 190.6). Only change vs R1: x_t extraction via ONE owner-lane shuffle
// (wave-uniform indices) instead of a 6-deep shfl_xor zero-sum chain; exact
// in both forms, strictly fewer DS ops, zero register cost.
//
// Block-local replication of the C=1000 prep reductions (8 KB, L2-hot; same
// 256-thread strided+tree structure as the original prep_kernel -> scalars
// bit-identical). Margin as post-correction:
//   s_adj = s - exp(x_t) + exp(x_t - bm)
__global__ __launch_bounds__(256) void main_kernel(const float* __restrict__ x,
                                                   const int*   __restrict__ targets,
                                                   const float* __restrict__ cls,
                                                   const float* __restrict__ diff,
                                                   const int*   __restrict__ epoch_p,
                                                   float*       __restrict__ partials) {
    __shared__ float smin[256], ssum[256], smax[256];
    const int tid = threadIdx.x;

    // ---- block-local prep reductions (identical to original prep_kernel) ----
    float mn = INFINITY, sm = 0.f, mx = -INFINITY;
    for (int c = tid; c < C_SZ; c += 256) {
        float v = cls[c];
        mn = fminf(mn, v);
        sm += v;
        mx = fmaxf(mx, diff[c]);
    }
    smin[tid] = mn; ssum[tid] = sm; smax[tid] = mx;
    __syncthreads();
    for (int s = 128; s > 0; s >>= 1) {
        if (tid < s) {
            smin[tid] = fminf(smin[tid], smin[tid + s]);
            ssum[tid] += ssum[tid + s];
            smax[tid] = fmaxf(smax[tid], smax[tid + s]);
        }
        __syncthreads();
    }
    __shared__ float sh_maxm, sh_minc, sh_wsc, sh_ee2;
    if (tid == 0) {
        const float minc = smin[0], sumc = ssum[0], maxd = smax[0];
        const float maxm = -logf(minc / sumc) - kMAGIC;
        const float maxw = 0.5f * maxd * maxd + 0.3f;   // ALPHA*d^P + BETA, P=2
        const int epoch = epoch_p[0];
        float ee2;
        if (epoch < 60)       ee2 = 0.f;
        else if (epoch >= 80) ee2 = 0.5f;               // ee=1, /2
        else                  ee2 = 0.5f * (float)(epoch - 60) / 20.0f;
        sh_maxm = maxm; sh_minc = minc; sh_wsc = maxm / maxw; sh_ee2 = ee2;
    }
    __syncthreads();
    const float maxm = sh_maxm, minc = sh_minc, wsc = sh_wsc, ee2 = sh_ee2;

    // ---- per-row loss ----
    const int lane = tid & 63;
    const int wv   = tid >> 6;
    const int gw   = blockIdx.x * 4 + wv;
    const int nw   = gridDim.x * 4;

    float acc = 0.f;
    for (int row = gw; row < B_SZ; row += nw) {
        const fvec4* __restrict__ xr = (const fvec4*)(x + (size_t)row * C_SZ);
        const int t = targets[row];                    // wave-uniform

        // Issue all 4 row loads up front (streaming, non-temporal).
        fvec4 v[4];
        #pragma unroll
        for (int k = 0; k < 4; ++k) {
            const int i4 = lane + 64 * k;
            if (i4 < NV4) v[k] = __builtin_nontemporal_load(&xr[i4]);
            else          v[k] = (fvec4){0.f, 0.f, 0.f, 0.f};
        }

        // per-row margin (L1/L2-hot 8 KB tables), same expression as prep's m1[t]
        const float bm = maxm * sqrtf(minc / cls[t])
                       + (0.5f * diff[t] * diff[t] + 0.3f) * wsc * ee2;

        float s = 0.f;
        #pragma unroll
        for (int k = 0; k < 4; ++k) {
            const int i4 = lane + 64 * k;
            if (i4 < NV4) {
                s += __expf(v[k].x);
                s += __expf(v[k].y);
                s += __expf(v[k].z);
                s += __expf(v[k].w);
            }
        }
        // wave-wide sum reduction (width 64)
        #pragma unroll
        for (int off = 32; off > 0; off >>= 1)
            s += __shfl_xor(s, off);

        // owner-lane extraction of x_t: all indices wave-uniform, ONE shuffle.
        // p is computed unconditionally from registers valid on every lane
        // (v[] is zero-filled past NV4), so the shfl source is always defined.
        const int t4 = t >> 2, tm = t & 3, kq = t4 >> 6, tl = t4 & 63;
        fvec4 vo = (kq == 0) ? v[0] : (kq == 1) ? v[1] : (kq == 2) ? v[2] : v[3];
        const float p = (tm & 2) ? ((tm & 1) ? vo.w : vo.z)
                                 : ((tm & 1) ? vo.y : vo.x);
        const float xt = __shfl(p, tl);

        // replace exp(x_t) by exp(x_t - bm); s >> exp(x_t), no cancellation risk
        const float xadj = xt - bm;
        const float sa = s - __expf(xt) + __expf(xadj);
        acc += __logf(sa) - xadj;
    }

    __shared__ float sw[4];
    if (lane == 0) sw[wv] = acc;
    __syncthreads();
    if (tid == 0)
        partials[blockIdx.x] = sw[0] + sw[1] + sw[2] + sw[3];
}

// ---------------- Kernel 2: final reduce -> loss ----------------
__global__ void finish_kernel(const float* __restrict__ partials, int n,
                              float* __restrict__ out) {
    __shared__ float sh[256];
    const int tid = threadIdx.x;
    float s = 0.f;
    for (int i = tid; i < n; i += 256) s += partials[i];
    sh[tid] = s;
    __syncthreads();
    for (int k = 128; k > 0; k >>= 1) {
        if (tid < k) sh[tid] += sh[tid + k];
        __syncthreads();
    }
    if (tid == 0) out[0] = sh[0] / (float)B_SZ;
}

extern "C" void kernel_launch(void* const* d_in, const int* in_sizes, int n_in,
                              void* d_out, int out_size, void* d_ws, size_t ws_size,
                              hipStream_t stream) {
    const float* x       = (const float*)d_in[0];
    const int*   targets = (const int*)d_in[1];
    const float* cls     = (const float*)d_in[2];
    const float* diff    = (const float*)d_in[3];
    const int*   epoch   = (const int*)d_in[4];
    float*       out     = (float*)d_out;

    float* partials = (float*)d_ws;          // grid floats

    const int grid = 2048;                   // 8192 waves, 4 rows each
    main_kernel<<<grid, 256, 0, stream>>>(x, targets, cls, diff, epoch, partials);

    finish_kernel<<<1, 256, 0, stream>>>(partials, grid, out);
}